// Round 13
// baseline (1631.696 us; speedup 1.0000x reference)
//
#include <hip/hip_runtime.h>
#include <stdint.h>

// GGNN round 13: f16 master state, split gather + f16 MFMA iteration.
//   s_t[n] = sum_{e:dst=n,type=t} xb[src[e]]   (k_gather3_b: wave/node, 3 interleaved chains)
//   k_mega2 (32-row block): gi = s@Wc^T (K=384), pack gi into the DEAD Ss LDS tile
//   (not registers - r12's register pack spilled ~14 dwords/thread, +90MB traffic),
//   gh = xb@W_hh^T (K=128), GRU in-register -> xb_new. Ping-pong xb.
// Peak acc regs 48 (was 96 in r11, 72+spill in r12) => (256,3) truly spill-free.

typedef _Float16 f16;
typedef _Float16 v8hf __attribute__((ext_vector_type(8)));
typedef _Float16 v2hf __attribute__((ext_vector_type(2)));
typedef float    v16f __attribute__((ext_vector_type(16)));

#define GI_F 147456   // 12 tiles * 24 ks * 512
#define GH_F 49152    // 12 tiles *  8 ks * 512

__device__ __forceinline__ float sigf(float a){
  return __fdividef(1.0f, 1.0f + __expf(-a));
}
__device__ __forceinline__ float tanhf_fast(float a){
  return 1.0f - __fdividef(2.0f, __expf(2.0f*a) + 1.0f);
}

__global__ void k_diag(float* out, int n, float v){
  int i = threadIdx.x; if(i<n) out[i] = v;
}

__global__ void k_embed(const int* __restrict__ xtype, const int* __restrict__ xtok,
                        const float* __restrict__ xsmall,
                        const float* __restrict__ temb, const float* __restrict__ kemb,
                        f16* __restrict__ xb, int N){
  int n = blockIdx.x; int j = threadIdx.x;
  if(n>=N) return;
  float v;
  if(j<32)       v = temb[xtype[n]*32 + j];
  else if(j<64)  v = kemb[xtok[n]*32 + (j-32)];
  else           v = xsmall[(size_t)n*64 + (j-64)];
  xb[(size_t)n*128 + j] = (f16)v;
}

// Wc[o2][K] = sum_k2 W_ih[o2,k2] * msg_W[K>>7][k2][K&127]
__global__ void k_wcomb(const float* __restrict__ W_ih, const float* __restrict__ msg_W,
                        float* __restrict__ Wc){
  int i = blockIdx.x*256 + threadIdx.x;
  if(i >= 147456) return;
  int o2 = i/384, K = i%384;
  const float* wr = W_ih + o2*128;
  const float* mc = msg_W + (K>>7)*16384 + (K&127);
  float acc = 0.f;
  #pragma unroll 4
  for(int k2=0;k2<128;k2++) acc += wr[k2]*mc[k2*128];
  Wc[i] = acc;
}

// mbp[t][o2] = sum_k2 W_ih[o2,k2]*msg_b[t,k2]
__global__ void k_mbp(const float* __restrict__ W_ih, const float* __restrict__ msg_b,
                      float* __restrict__ mbp){
  int i = blockIdx.x*256 + threadIdx.x;
  if(i >= 1152) return;
  int t = i/384, o2 = i%384;
  const float* wr = W_ih + o2*128;
  const float* mb = msg_b + t*128;
  float acc = 0.f;
  #pragma unroll 4
  for(int k2=0;k2<128;k2++) acc += wr[k2]*mb[k2];
  mbp[i] = acc;
}

// Pack weights f16, MFMA B-frag order: n = tile*32+(lane&31), k = ks*16+(lane>>5)*8+j
__global__ void k_wprep(const float* __restrict__ Wc, const float* __restrict__ W_hh,
                        f16* __restrict__ WpF){
  int i = blockIdx.x*256 + threadIdx.x;
  if(i >= GI_F + GH_F) return;
  float w; int lane, j;
  if(i < GI_F){
    int grp = i/512, rem = i%512;
    lane = rem/8; j = rem%8;
    int tile = grp/24, ks = grp%24;
    int n = tile*32 + (lane&31);
    int k = ks*16 + (lane>>5)*8 + j;
    w = Wc[n*384 + k];
  } else {
    int i2 = i - GI_F;
    int grp = i2/512, rem = i2%512;
    lane = rem/8; j = rem%8;
    int tile = grp/8, ks = grp%8;
    int n = tile*32 + (lane&31);
    int k = ks*16 + (lane>>5)*8 + j;
    w = W_hh[n*128 + k];
  }
  WpF[i] = (f16)w;
}

__global__ void k_hist3(const int* __restrict__ dst, const int* __restrict__ et,
                        int* __restrict__ deg3, int E){
  int e = blockIdx.x*blockDim.x + threadIdx.x;
  if(e<E) atomicAdd(&deg3[dst[e]*3 + et[e]], 1);
}

__global__ void k_scan1(const int* __restrict__ deg, int n, int* __restrict__ part, int* __restrict__ bsum){
  __shared__ int s[256];
  int t = threadIdx.x;
  int base = blockIdx.x*1024 + t*4;
  int v[4]; int sum=0;
  #pragma unroll
  for(int k=0;k<4;k++){ int i=base+k; int d=(i<n)?deg[i]:0; sum+=d; v[k]=sum; }
  s[t]=sum; __syncthreads();
  for(int off=1;off<256;off<<=1){
    int add = (t>=off)? s[t-off] : 0;
    __syncthreads();
    s[t]+=add;
    __syncthreads();
  }
  int excl = (t>0)? s[t-1] : 0;
  #pragma unroll
  for(int k=0;k<4;k++){ int i=base+k; if(i<n) part[i]=v[k]+excl; }
  if(t==255) bsum[blockIdx.x] = s[255];
}

__global__ void k_scan2(const int* __restrict__ bsum, int nb, int* __restrict__ carry){
  if(threadIdx.x==0 && blockIdx.x==0){
    int c=0;
    for(int b=0;b<nb;b++){ carry[b]=c; c+=bsum[b]; }
  }
}

__global__ void k_finalize(const int* __restrict__ part, const int* __restrict__ deg,
                           const int* __restrict__ carry, int n,
                           int* __restrict__ rowptr, int* __restrict__ cursor){
  int i = blockIdx.x*blockDim.x + threadIdx.x;
  if(i>=n) return;
  int incl = part[i] + carry[i>>10];
  rowptr[i+1] = incl;
  cursor[i] = incl - deg[i];
  if(i==0) rowptr[0]=0;
}

__global__ void k_fill3(const int* __restrict__ src, const int* __restrict__ dst,
                        const int* __restrict__ et, int* __restrict__ cursor,
                        int* __restrict__ pay, int E){
  int e = blockIdx.x*blockDim.x + threadIdx.x;
  if(e>=E) return;
  int pos = atomicAdd(&cursor[dst[e]*3 + et[e]], 1);
  pay[pos] = src[e];
}

// gather: one wave per node, the node's 3 type-bin chains interleaved (3x load ILP).
__global__ void k_gather3_b(const f16* __restrict__ xb, const int* __restrict__ rp3,
                            const int* __restrict__ pay, f16* __restrict__ s, int N){
  int n = blockIdx.x*4 + (threadIdx.x>>6);
  if(n >= N) return;
  int lane = threadIdx.x & 63;
  int c = lane*2;
  int b = n*3;
  int i0 = rp3[b],   e0 = rp3[b+1];
  int i1 = e0,       e1 = rp3[b+2];
  int i2 = e1,       e2 = rp3[b+3];
  float a0=0.f,b0=0.f,a1=0.f,b1=0.f,a2=0.f,b2=0.f;
  while(i0<e0 && i1<e1 && i2<e2){
    int p0 = pay[i0], p1 = pay[i1], p2 = pay[i2];
    v2hf u0 = *(const v2hf*)&xb[(size_t)p0*128 + c];
    v2hf u1 = *(const v2hf*)&xb[(size_t)p1*128 + c];
    v2hf u2 = *(const v2hf*)&xb[(size_t)p2*128 + c];
    a0 += (float)u0[0]; b0 += (float)u0[1];
    a1 += (float)u1[0]; b1 += (float)u1[1];
    a2 += (float)u2[0]; b2 += (float)u2[1];
    i0++; i1++; i2++;
  }
  for(; i0<e0; i0++){ v2hf u = *(const v2hf*)&xb[(size_t)pay[i0]*128 + c]; a0+=(float)u[0]; b0+=(float)u[1]; }
  for(; i1<e1; i1++){ v2hf u = *(const v2hf*)&xb[(size_t)pay[i1]*128 + c]; a1+=(float)u[0]; b1+=(float)u[1]; }
  for(; i2<e2; i2++){ v2hf u = *(const v2hf*)&xb[(size_t)pay[i2]*128 + c]; a2+=(float)u[0]; b2+=(float)u[1]; }
  size_t o = (size_t)n*384 + c;
  v2hf t;
  t[0]=(f16)a0; t[1]=(f16)b0; *(v2hf*)&s[o]     = t;
  t[0]=(f16)a1; t[1]=(f16)b1; *(v2hf*)&s[o+128] = t;
  t[0]=(f16)a2; t[1]=(f16)b2; *(v2hf*)&s[o+256] = t;
}

// Fused gi+gh GEMM + GRU, f16 master. 32 rows/block, 256 threads (4 waves).
// Wave w col-tiles {w,w+4,w+8} => feature slice jf in [32w,32w+32) across all
// 3 gates for gi AND gh => GRU in-register. gi packed into the dead Ss tile
// (barrier-guarded), so peak live acc = 48 regs -> no spill at (256,3).
#define SSTR 392   // 384+8
#define XSTR 136   // 128+8
__global__ __launch_bounds__(256,3) void k_mega2(
    const f16* __restrict__ xb_old, f16* __restrict__ xb_new,
    const f16* __restrict__ s, const f16* __restrict__ WpF,
    const int* __restrict__ deg3, const float* __restrict__ mbp,
    const float* __restrict__ b_ih, const float* __restrict__ b_hh, int M)
{
  __shared__ f16 Ss[32*SSTR];   // 24.5 KB: s tile, then packed gi
  __shared__ f16 Ax[32*XSTR];   //  8.5 KB
  __shared__ float Dg[96];      // deg3 for this block's 32 rows
  int tid = threadIdx.x, lane = tid & 63, w = tid >> 6;
  int lrow = lane & 31, q = lane >> 5;
  int row0 = blockIdx.x * 32;

  // stage xb rows -> Ax: 512 chunks, 2/thread
  #pragma unroll
  for(int p=0;p<2;p++){
    int ch = tid + p*256;
    int row = ch>>4, c8 = (ch&15)*8;
    int gr = row0 + row; if(gr >= M) gr = M-1;
    *(v8hf*)&Ax[row*XSTR + c8] = *(const v8hf*)(xb_old + (size_t)gr*128 + c8);
  }
  // stage s rows -> Ss: 1536 chunks, 6/thread
  #pragma unroll
  for(int p=0;p<6;p++){
    int ch = tid + p*256;
    int row = ch/48, c8 = (ch%48)*8;
    int gr = row0 + row; if(gr >= M) gr = M-1;
    *(v8hf*)&Ss[row*SSTR + c8] = *(const v8hf*)(s + (size_t)gr*384 + c8);
  }
  // stage deg3 -> Dg
  if(tid < 96){
    int node = row0 + tid/3;
    Dg[tid] = (node < M) ? (float)deg3[node*3 + (tid - (tid/3)*3)] : 0.f;
  }
  __syncthreads();

  int jf = w*32 + lrow;
  int rq4 = 4*q;

  // ---- gi phase: K=384 over Ss ----
  {
    v16f agi[3] = {};
    #pragma unroll
    for(int ks=0; ks<24; ks++){
      int kb = ks*16 + q*8;
      v8hf a0 = *(const v8hf*)&Ss[lrow*SSTR + kb];
      #pragma unroll
      for(int ct=0; ct<3; ct++){
        int tile = ct*4 + w;
        v8hf bh = *(const v8hf*)(WpF + (size_t)(tile*24 + ks)*512 + lane*8);
        agi[ct] = __builtin_amdgcn_mfma_f32_32x32x16_f16(a0, bh, agi[ct], 0,0,0);
      }
    }
    __syncthreads();   // all waves done READING Ss before it is overwritten
    // pack gi into Ss (own slots only, no cross-thread sharing)
    #pragma unroll
    for(int r=0;r<16;r++){
      int gl = (r&3) + 8*(r>>2) + rq4;
      #pragma unroll
      for(int ct=0; ct<3; ct++)
        Ss[gl*SSTR + ct*128 + jf] = (f16)agi[ct][r];
    }
  }

  // ---- gh phase: K=128 over Ax (only 48 acc regs live now) ----
  v16f agh[3] = {};
  #pragma unroll
  for(int ks=0; ks<8; ks++){
    int kb = ks*16 + q*8;
    v8hf a0 = *(const v8hf*)&Ax[lrow*XSTR + kb];
    #pragma unroll
    for(int ct=0; ct<3; ct++){
      int tile = ct*4 + w;
      v8hf bh = *(const v8hf*)(WpF + GI_F + (size_t)(tile*8 + ks)*512 + lane*8);
      agh[ct] = __builtin_amdgcn_mfma_f32_32x32x16_f16(a0, bh, agh[ct], 0,0,0);
    }
  }

  // GRU epilogue in-register. jf = this lane's feature; gi from LDS; x_old from Ax.
  float bi0 = b_ih[jf],     bh0 = b_hh[jf];
  float bi1 = b_ih[128+jf], bh1 = b_hh[128+jf];
  float bi2 = b_ih[256+jf], bh2 = b_hh[256+jf];
  float mb[3][3];
  #pragma unroll
  for(int t=0;t<3;t++){
    mb[t][0] = mbp[t*384 + jf];
    mb[t][1] = mbp[t*384 + 128 + jf];
    mb[t][2] = mbp[t*384 + 256 + jf];
  }
  #pragma unroll
  for(int r=0;r<16;r++){
    int gl = (r&3) + 8*(r>>2) + rq4;          // local row 0..31
    float d0 = Dg[gl*3], d1 = Dg[gl*3+1], d2 = Dg[gl*3+2];
    float g0 = (float)Ss[gl*SSTR + jf];
    float g1 = (float)Ss[gl*SSTR + 128 + jf];
    float g2 = (float)Ss[gl*SSTR + 256 + jf];
    float ir  = g0 + bi0 + d0*mb[0][0] + d1*mb[1][0] + d2*mb[2][0];
    float iz  = g1 + bi1 + d0*mb[0][1] + d1*mb[1][1] + d2*mb[2][1];
    float in_ = g2 + bi2 + d0*mb[0][2] + d1*mb[1][2] + d2*mb[2][2];
    float hr  = agh[0][r] + bh0;
    float hz  = agh[1][r] + bh1;
    float hn  = agh[2][r] + bh2;
    float rg = sigf(ir + hr);
    float zg = sigf(iz + hz);
    float nn = tanhf_fast(in_ + rg*hn);
    float xo = (float)Ax[gl*XSTR + jf];
    Ax[gl*XSTR + jf] = (f16)((1.f - zg)*nn + zg*xo);   // in-place, own slot
  }
  __syncthreads();
  // coalesced writeback from Ax
  #pragma unroll
  for(int p=0;p<2;p++){
    int ch = tid + p*256;
    int row = ch>>4, c8 = (ch&15)*8;
    int gr = row0 + row;
    if(gr < M)
      *(v8hf*)(xb_new + (size_t)gr*128 + c8) = *(const v8hf*)&Ax[row*XSTR + c8];
  }
}

__device__ __forceinline__ int lb_batch(const int* __restrict__ batch, int N, int g){
  int lo=0, hi=N;
  while(lo<hi){ int mid=(lo+hi)>>1; if(batch[mid]<g) lo=mid+1; else hi=mid; }
  return lo;
}

__global__ void k_pool2(const f16* __restrict__ xb, const int* __restrict__ batch,
                        float* __restrict__ pooled, int N){
  int g = blockIdx.x, slice = blockIdx.y;
  int j = threadIdx.x;
  int lo = lb_batch(batch,N,g), hi = lb_batch(batch,N,g+1);
  float acc = 0.f;
  for(int r=lo+slice; r<hi; r+=32) acc += (float)xb[(size_t)r*128 + j];
  atomicAdd(&pooled[g*128+j], acc);
}

__global__ void k_head(const float* __restrict__ pooled, const int* __restrict__ batch, int N,
                       const float* __restrict__ W1, const float* __restrict__ b1,
                       const float* __restrict__ W2, const float* __restrict__ b2,
                       float* __restrict__ out){
  int g = blockIdx.x; int j = threadIdx.x;
  __shared__ float p[128];
  __shared__ float red[128];
  int lo = lb_batch(batch,N,g), hi = lb_batch(batch,N,g+1);
  float c = (float)(hi-lo); if(c < 1.f) c = 1.f;
  p[j] = pooled[g*128+j] / c;
  __syncthreads();
  float acc = b1[j];
  #pragma unroll 4
  for(int i=0;i<128;i++) acc += W1[j*128+i]*p[i];
  float v = (acc>0.f?acc:0.f) * W2[j];
  red[j] = v; __syncthreads();
  for(int s=64;s>0;s>>=1){ if(j<s) red[j]+=red[j+s]; __syncthreads(); }
  if(j==0) out[g] = red[0] + b2[0];
}

extern "C" void kernel_launch(void* const* d_in, const int* in_sizes, int n_in,
                              void* d_out, int out_size, void* d_ws, size_t ws_size,
                              hipStream_t stream){
  const int*   x_type    = (const int*)d_in[0];
  const int*   x_tok     = (const int*)d_in[1];
  const float* x_small   = (const float*)d_in[2];
  const int*   edge_index= (const int*)d_in[3];
  const int*   edge_type = (const int*)d_in[4];
  const int*   batch     = (const int*)d_in[5];
  const float* type_emb  = (const float*)d_in[6];
  const float* tok_emb   = (const float*)d_in[7];
  const float* msg_W     = (const float*)d_in[8];
  const float* msg_b     = (const float*)d_in[9];
  const float* W_ih      = (const float*)d_in[10];
  const float* W_hh      = (const float*)d_in[11];
  const float* b_ih      = (const float*)d_in[12];
  const float* b_hh      = (const float*)d_in[13];
  const float* pW1       = (const float*)d_in[14];
  const float* pb1       = (const float*)d_in[15];
  const float* pW2       = (const float*)d_in[16];
  const float* pb2       = (const float*)d_in[17];
  float* out = (float*)d_out;

  int N = in_sizes[0];
  int E = in_sizes[3]/2;
  const int* src = edge_index;
  const int* dst = edge_index + E;
  int n3 = 3*N;
  int nch = (n3+1023)/1024;

  char* w = (char*)d_ws;
  size_t off = 0;
  auto alloc = [&](size_t bytes)->char*{ char* p = w + off; off += (bytes + 511) & ~511ull; return p; };
  f16*   xb0    = (f16*)alloc((size_t)N*128*2);       // ping (25.6 MB)
  f16*   xb1    = (f16*)alloc((size_t)N*128*2);       // pong (25.6 MB)
  f16*   s      = (f16*)alloc((size_t)N*384*2);       // gathered sums (76.8 MB)
  int*   deg3   = (int*)alloc((size_t)n3*4);
  int*   part   = (int*)alloc((size_t)n3*4);
  int*   rp3    = (int*)alloc((size_t)(n3+1)*4);
  int*   cursor = (int*)alloc((size_t)n3*4);
  int*   pay    = (int*)alloc((size_t)E*4);
  int*   bsum   = (int*)alloc((size_t)nch*4);
  int*   carry  = (int*)alloc((size_t)nch*4);
  float* Wc     = (float*)alloc((size_t)147456*4);
  f16*   WpF    = (f16*)alloc((size_t)(GI_F+GH_F)*2);
  float* mbp    = (float*)alloc((size_t)1152*4);
  float* pooled = (float*)alloc(64*128*4);
  if(off > ws_size){
    k_diag<<<1,64,0,stream>>>(out, out_size, 1.0e6f + (float)(ws_size>>20));
    return;
  }

  const int tb = 256;
  hipMemsetAsync(deg3, 0, (size_t)n3*4, stream);
  k_wcomb   <<<576, 256, 0, stream>>>(W_ih, msg_W, Wc);
  k_mbp     <<<5, 256, 0, stream>>>(W_ih, msg_b, mbp);
  k_wprep   <<<(GI_F+GH_F+255)/256, 256, 0, stream>>>(Wc, W_hh, WpF);
  k_hist3   <<<(E+tb-1)/tb, tb, 0, stream>>>(dst, edge_type, deg3, E);
  k_scan1   <<<nch, 256, 0, stream>>>(deg3, n3, part, bsum);
  k_scan2   <<<1, 64, 0, stream>>>(bsum, nch, carry);
  k_finalize<<<(n3+tb-1)/tb, tb, 0, stream>>>(part, deg3, carry, n3, rp3, cursor);
  k_fill3   <<<(E+tb-1)/tb, tb, 0, stream>>>(src, dst, edge_type, cursor, pay, E);
  k_embed   <<<N, 128, 0, stream>>>(x_type, x_tok, x_small, type_emb, tok_emb, xb0, N);

  int nblk = (N+31)/32;
  f16* xin = xb0;
  f16* xout = xb1;
  for(int it=0; it<8; it++){
    k_gather3_b<<<(N+3)/4, 256, 0, stream>>>(xin, rp3, pay, s, N);
    k_mega2    <<<nblk, 256, 0, stream>>>(xin, xout, s, WpF, deg3, mbp, b_ih, b_hh, N);
    f16* tmp = xin; xin = xout; xout = tmp;
  }
  // final state is in xin after the swap
  hipMemsetAsync(pooled, 0, 64*128*4, stream);
  k_pool2<<<dim3(64,32), 128, 0, stream>>>(xin, batch, pooled, N);
  k_head <<<64, 128, 0, stream>>>(pooled, batch, N, pW1, pb1, pW2, pb2, out);
}

// Round 14
// 1282.450 us; speedup vs baseline: 1.2723x; 1.2723x over previous
//
#include <hip/hip_runtime.h>
#include <stdint.h>

// GGNN round 14: f16 master state, split gather + f16 MFMA iteration.
// == round-12 structure (gi-first + in-REGISTER f16 pack of gi) with
// __launch_bounds__(256,2): r12's (256,3) cap forced ~14 dw/thread scratch
// spill (+90MB traffic) yet never achieved the 3rd block (occ stayed 28%);
// r13's LDS-pack removed the spill but its extra barrier serialized the
// gi/gh phases (85 -> 138us). Uncapped regs keep the pack in-register.

typedef _Float16 f16;
typedef _Float16 v8hf __attribute__((ext_vector_type(8)));
typedef _Float16 v2hf __attribute__((ext_vector_type(2)));
typedef float    v16f __attribute__((ext_vector_type(16)));

#define GI_F 147456   // 12 tiles * 24 ks * 512
#define GH_F 49152    // 12 tiles *  8 ks * 512

__device__ __forceinline__ float sigf(float a){
  return __fdividef(1.0f, 1.0f + __expf(-a));
}
__device__ __forceinline__ float tanhf_fast(float a){
  return 1.0f - __fdividef(2.0f, __expf(2.0f*a) + 1.0f);
}

__global__ void k_diag(float* out, int n, float v){
  int i = threadIdx.x; if(i<n) out[i] = v;
}

__global__ void k_embed(const int* __restrict__ xtype, const int* __restrict__ xtok,
                        const float* __restrict__ xsmall,
                        const float* __restrict__ temb, const float* __restrict__ kemb,
                        f16* __restrict__ xb, int N){
  int n = blockIdx.x; int j = threadIdx.x;
  if(n>=N) return;
  float v;
  if(j<32)       v = temb[xtype[n]*32 + j];
  else if(j<64)  v = kemb[xtok[n]*32 + (j-32)];
  else           v = xsmall[(size_t)n*64 + (j-64)];
  xb[(size_t)n*128 + j] = (f16)v;
}

// Wc[o2][K] = sum_k2 W_ih[o2,k2] * msg_W[K>>7][k2][K&127]
__global__ void k_wcomb(const float* __restrict__ W_ih, const float* __restrict__ msg_W,
                        float* __restrict__ Wc){
  int i = blockIdx.x*256 + threadIdx.x;
  if(i >= 147456) return;
  int o2 = i/384, K = i%384;
  const float* wr = W_ih + o2*128;
  const float* mc = msg_W + (K>>7)*16384 + (K&127);
  float acc = 0.f;
  #pragma unroll 4
  for(int k2=0;k2<128;k2++) acc += wr[k2]*mc[k2*128];
  Wc[i] = acc;
}

// mbp[t][o2] = sum_k2 W_ih[o2,k2]*msg_b[t,k2]
__global__ void k_mbp(const float* __restrict__ W_ih, const float* __restrict__ msg_b,
                      float* __restrict__ mbp){
  int i = blockIdx.x*256 + threadIdx.x;
  if(i >= 1152) return;
  int t = i/384, o2 = i%384;
  const float* wr = W_ih + o2*128;
  const float* mb = msg_b + t*128;
  float acc = 0.f;
  #pragma unroll 4
  for(int k2=0;k2<128;k2++) acc += wr[k2]*mb[k2];
  mbp[i] = acc;
}

// Pack weights f16, MFMA B-frag order: n = tile*32+(lane&31), k = ks*16+(lane>>5)*8+j
__global__ void k_wprep(const float* __restrict__ Wc, const float* __restrict__ W_hh,
                        f16* __restrict__ WpF){
  int i = blockIdx.x*256 + threadIdx.x;
  if(i >= GI_F + GH_F) return;
  float w; int lane, j;
  if(i < GI_F){
    int grp = i/512, rem = i%512;
    lane = rem/8; j = rem%8;
    int tile = grp/24, ks = grp%24;
    int n = tile*32 + (lane&31);
    int k = ks*16 + (lane>>5)*8 + j;
    w = Wc[n*384 + k];
  } else {
    int i2 = i - GI_F;
    int grp = i2/512, rem = i2%512;
    lane = rem/8; j = rem%8;
    int tile = grp/8, ks = grp%8;
    int n = tile*32 + (lane&31);
    int k = ks*16 + (lane>>5)*8 + j;
    w = W_hh[n*128 + k];
  }
  WpF[i] = (f16)w;
}

__global__ void k_hist3(const int* __restrict__ dst, const int* __restrict__ et,
                        int* __restrict__ deg3, int E){
  int e = blockIdx.x*blockDim.x + threadIdx.x;
  if(e<E) atomicAdd(&deg3[dst[e]*3 + et[e]], 1);
}

__global__ void k_scan1(const int* __restrict__ deg, int n, int* __restrict__ part, int* __restrict__ bsum){
  __shared__ int s[256];
  int t = threadIdx.x;
  int base = blockIdx.x*1024 + t*4;
  int v[4]; int sum=0;
  #pragma unroll
  for(int k=0;k<4;k++){ int i=base+k; int d=(i<n)?deg[i]:0; sum+=d; v[k]=sum; }
  s[t]=sum; __syncthreads();
  for(int off=1;off<256;off<<=1){
    int add = (t>=off)? s[t-off] : 0;
    __syncthreads();
    s[t]+=add;
    __syncthreads();
  }
  int excl = (t>0)? s[t-1] : 0;
  #pragma unroll
  for(int k=0;k<4;k++){ int i=base+k; if(i<n) part[i]=v[k]+excl; }
  if(t==255) bsum[blockIdx.x] = s[255];
}

__global__ void k_scan2(const int* __restrict__ bsum, int nb, int* __restrict__ carry){
  if(threadIdx.x==0 && blockIdx.x==0){
    int c=0;
    for(int b=0;b<nb;b++){ carry[b]=c; c+=bsum[b]; }
  }
}

__global__ void k_finalize(const int* __restrict__ part, const int* __restrict__ deg,
                           const int* __restrict__ carry, int n,
                           int* __restrict__ rowptr, int* __restrict__ cursor){
  int i = blockIdx.x*blockDim.x + threadIdx.x;
  if(i>=n) return;
  int incl = part[i] + carry[i>>10];
  rowptr[i+1] = incl;
  cursor[i] = incl - deg[i];
  if(i==0) rowptr[0]=0;
}

__global__ void k_fill3(const int* __restrict__ src, const int* __restrict__ dst,
                        const int* __restrict__ et, int* __restrict__ cursor,
                        int* __restrict__ pay, int E){
  int e = blockIdx.x*blockDim.x + threadIdx.x;
  if(e>=E) return;
  int pos = atomicAdd(&cursor[dst[e]*3 + et[e]], 1);
  pay[pos] = src[e];
}

// gather: one wave per node, the node's 3 type-bin chains interleaved (3x load ILP).
__global__ void k_gather3_b(const f16* __restrict__ xb, const int* __restrict__ rp3,
                            const int* __restrict__ pay, f16* __restrict__ s, int N){
  int n = blockIdx.x*4 + (threadIdx.x>>6);
  if(n >= N) return;
  int lane = threadIdx.x & 63;
  int c = lane*2;
  int b = n*3;
  int i0 = rp3[b],   e0 = rp3[b+1];
  int i1 = e0,       e1 = rp3[b+2];
  int i2 = e1,       e2 = rp3[b+3];
  float a0=0.f,b0=0.f,a1=0.f,b1=0.f,a2=0.f,b2=0.f;
  while(i0<e0 && i1<e1 && i2<e2){
    int p0 = pay[i0], p1 = pay[i1], p2 = pay[i2];
    v2hf u0 = *(const v2hf*)&xb[(size_t)p0*128 + c];
    v2hf u1 = *(const v2hf*)&xb[(size_t)p1*128 + c];
    v2hf u2 = *(const v2hf*)&xb[(size_t)p2*128 + c];
    a0 += (float)u0[0]; b0 += (float)u0[1];
    a1 += (float)u1[0]; b1 += (float)u1[1];
    a2 += (float)u2[0]; b2 += (float)u2[1];
    i0++; i1++; i2++;
  }
  for(; i0<e0; i0++){ v2hf u = *(const v2hf*)&xb[(size_t)pay[i0]*128 + c]; a0+=(float)u[0]; b0+=(float)u[1]; }
  for(; i1<e1; i1++){ v2hf u = *(const v2hf*)&xb[(size_t)pay[i1]*128 + c]; a1+=(float)u[0]; b1+=(float)u[1]; }
  for(; i2<e2; i2++){ v2hf u = *(const v2hf*)&xb[(size_t)pay[i2]*128 + c]; a2+=(float)u[0]; b2+=(float)u[1]; }
  size_t o = (size_t)n*384 + c;
  v2hf t;
  t[0]=(f16)a0; t[1]=(f16)b0; *(v2hf*)&s[o]     = t;
  t[0]=(f16)a1; t[1]=(f16)b1; *(v2hf*)&s[o+128] = t;
  t[0]=(f16)a2; t[1]=(f16)b2; *(v2hf*)&s[o+256] = t;
}

// Fused gi+gh GEMM + GRU, f16 master. 32 rows/block, 256 threads (4 waves).
// Wave w col-tiles {w,w+4,w+8} => feature slice jf in [32w,32w+32) across all
// 3 gates for gi AND gh => GRU in-register. Order: gi MFMAs -> pack agi to f16
// pairs in REGISTERS -> gh MFMAs -> epilogue. (256,2): uncapped regs, no spill.
#define SSTR 392   // 384+8
#define XSTR 136   // 128+8
__global__ __launch_bounds__(256,2) void k_mega2(
    const f16* __restrict__ xb_old, f16* __restrict__ xb_new,
    const f16* __restrict__ s, const f16* __restrict__ WpF,
    const int* __restrict__ deg3, const float* __restrict__ mbp,
    const float* __restrict__ b_ih, const float* __restrict__ b_hh, int M)
{
  __shared__ f16 Ss[32*SSTR];   // 24.5 KB
  __shared__ f16 Ax[32*XSTR];   //  8.5 KB
  __shared__ float Dg[96];      // deg3 for this block's 32 rows
  int tid = threadIdx.x, lane = tid & 63, w = tid >> 6;
  int lrow = lane & 31, q = lane >> 5;
  int row0 = blockIdx.x * 32;

  // stage xb rows -> Ax: 512 chunks, 2/thread
  #pragma unroll
  for(int p=0;p<2;p++){
    int ch = tid + p*256;
    int row = ch>>4, c8 = (ch&15)*8;
    int gr = row0 + row; if(gr >= M) gr = M-1;
    *(v8hf*)&Ax[row*XSTR + c8] = *(const v8hf*)(xb_old + (size_t)gr*128 + c8);
  }
  // stage s rows -> Ss: 1536 chunks, 6/thread
  #pragma unroll
  for(int p=0;p<6;p++){
    int ch = tid + p*256;
    int row = ch/48, c8 = (ch%48)*8;
    int gr = row0 + row; if(gr >= M) gr = M-1;
    *(v8hf*)&Ss[row*SSTR + c8] = *(const v8hf*)(s + (size_t)gr*384 + c8);
  }
  // stage deg3 -> Dg
  if(tid < 96){
    int node = row0 + tid/3;
    Dg[tid] = (node < M) ? (float)deg3[node*3 + (tid - (tid/3)*3)] : 0.f;
  }
  __syncthreads();

  // ---- gi phase: K=384 over Ss ----
  v16f agi[3] = {};
  #pragma unroll
  for(int ks=0; ks<24; ks++){
    int kb = ks*16 + q*8;
    v8hf a0 = *(const v8hf*)&Ss[lrow*SSTR + kb];
    #pragma unroll
    for(int ct=0; ct<3; ct++){
      int tile = ct*4 + w;
      v8hf bh = *(const v8hf*)(WpF + (size_t)(tile*24 + ks)*512 + lane*8);
      agi[ct] = __builtin_amdgcn_mfma_f32_32x32x16_f16(a0, bh, agi[ct], 0,0,0);
    }
  }
  // pack agi -> f16 pairs in registers (frees 48 -> 24 regs; no cap => no spill)
  v2hf gip[3][8];
  #pragma unroll
  for(int ct=0; ct<3; ct++)
    #pragma unroll
    for(int rp=0; rp<8; rp++){
      v2hf t; t[0] = (f16)agi[ct][2*rp]; t[1] = (f16)agi[ct][2*rp+1];
      gip[ct][rp] = t;
    }

  // ---- gh phase: K=128 over Ax ----
  v16f agh[3] = {};
  #pragma unroll
  for(int ks=0; ks<8; ks++){
    int kb = ks*16 + q*8;
    v8hf a0 = *(const v8hf*)&Ax[lrow*XSTR + kb];
    #pragma unroll
    for(int ct=0; ct<3; ct++){
      int tile = ct*4 + w;
      v8hf bh = *(const v8hf*)(WpF + GI_F + (size_t)(tile*8 + ks)*512 + lane*8);
      agh[ct] = __builtin_amdgcn_mfma_f32_32x32x16_f16(a0, bh, agh[ct], 0,0,0);
    }
  }

  // GRU epilogue in-register. jf = this lane's feature; x_old from LDS.
  int jf = w*32 + lrow;
  float bi0 = b_ih[jf],     bh0 = b_hh[jf];
  float bi1 = b_ih[128+jf], bh1 = b_hh[128+jf];
  float bi2 = b_ih[256+jf], bh2 = b_hh[256+jf];
  float mb[3][3];
  #pragma unroll
  for(int t=0;t<3;t++){
    mb[t][0] = mbp[t*384 + jf];
    mb[t][1] = mbp[t*384 + 128 + jf];
    mb[t][2] = mbp[t*384 + 256 + jf];
  }
  int rq4 = 4*q;
  #pragma unroll
  for(int r=0;r<16;r++){
    int gl = (r&3) + 8*(r>>2) + rq4;          // local row 0..31
    float d0 = Dg[gl*3], d1 = Dg[gl*3+1], d2 = Dg[gl*3+2];
    float g0 = (float)gip[0][r>>1][r&1];
    float g1 = (float)gip[1][r>>1][r&1];
    float g2 = (float)gip[2][r>>1][r&1];
    float ir  = g0 + bi0 + d0*mb[0][0] + d1*mb[1][0] + d2*mb[2][0];
    float iz  = g1 + bi1 + d0*mb[0][1] + d1*mb[1][1] + d2*mb[2][1];
    float in_ = g2 + bi2 + d0*mb[0][2] + d1*mb[1][2] + d2*mb[2][2];
    float hr  = agh[0][r] + bh0;
    float hz  = agh[1][r] + bh1;
    float hn  = agh[2][r] + bh2;
    float rg = sigf(ir + hr);
    float zg = sigf(iz + hz);
    float nn = tanhf_fast(in_ + rg*hn);
    float xo = (float)Ax[gl*XSTR + jf];
    Ax[gl*XSTR + jf] = (f16)((1.f - zg)*nn + zg*xo);   // in-place, own slot
  }
  __syncthreads();
  // coalesced writeback from Ax
  #pragma unroll
  for(int p=0;p<2;p++){
    int ch = tid + p*256;
    int row = ch>>4, c8 = (ch&15)*8;
    int gr = row0 + row;
    if(gr < M)
      *(v8hf*)(xb_new + (size_t)gr*128 + c8) = *(const v8hf*)&Ax[row*XSTR + c8];
  }
}

__device__ __forceinline__ int lb_batch(const int* __restrict__ batch, int N, int g){
  int lo=0, hi=N;
  while(lo<hi){ int mid=(lo+hi)>>1; if(batch[mid]<g) lo=mid+1; else hi=mid; }
  return lo;
}

__global__ void k_pool2(const f16* __restrict__ xb, const int* __restrict__ batch,
                        float* __restrict__ pooled, int N){
  int g = blockIdx.x, slice = blockIdx.y;
  int j = threadIdx.x;
  int lo = lb_batch(batch,N,g), hi = lb_batch(batch,N,g+1);
  float acc = 0.f;
  for(int r=lo+slice; r<hi; r+=32) acc += (float)xb[(size_t)r*128 + j];
  atomicAdd(&pooled[g*128+j], acc);
}

__global__ void k_head(const float* __restrict__ pooled, const int* __restrict__ batch, int N,
                       const float* __restrict__ W1, const float* __restrict__ b1,
                       const float* __restrict__ W2, const float* __restrict__ b2,
                       float* __restrict__ out){
  int g = blockIdx.x; int j = threadIdx.x;
  __shared__ float p[128];
  __shared__ float red[128];
  int lo = lb_batch(batch,N,g), hi = lb_batch(batch,N,g+1);
  float c = (float)(hi-lo); if(c < 1.f) c = 1.f;
  p[j] = pooled[g*128+j] / c;
  __syncthreads();
  float acc = b1[j];
  #pragma unroll 4
  for(int i=0;i<128;i++) acc += W1[j*128+i]*p[i];
  float v = (acc>0.f?acc:0.f) * W2[j];
  red[j] = v; __syncthreads();
  for(int s=64;s>0;s>>=1){ if(j<s) red[j]+=red[j+s]; __syncthreads(); }
  if(j==0) out[g] = red[0] + b2[0];
}

extern "C" void kernel_launch(void* const* d_in, const int* in_sizes, int n_in,
                              void* d_out, int out_size, void* d_ws, size_t ws_size,
                              hipStream_t stream){
  const int*   x_type    = (const int*)d_in[0];
  const int*   x_tok     = (const int*)d_in[1];
  const float* x_small   = (const float*)d_in[2];
  const int*   edge_index= (const int*)d_in[3];
  const int*   edge_type = (const int*)d_in[4];
  const int*   batch     = (const int*)d_in[5];
  const float* type_emb  = (const float*)d_in[6];
  const float* tok_emb   = (const float*)d_in[7];
  const float* msg_W     = (const float*)d_in[8];
  const float* msg_b     = (const float*)d_in[9];
  const float* W_ih      = (const float*)d_in[10];
  const float* W_hh      = (const float*)d_in[11];
  const float* b_ih      = (const float*)d_in[12];
  const float* b_hh      = (const float*)d_in[13];
  const float* pW1       = (const float*)d_in[14];
  const float* pb1       = (const float*)d_in[15];
  const float* pW2       = (const float*)d_in[16];
  const float* pb2       = (const float*)d_in[17];
  float* out = (float*)d_out;

  int N = in_sizes[0];
  int E = in_sizes[3]/2;
  const int* src = edge_index;
  const int* dst = edge_index + E;
  int n3 = 3*N;
  int nch = (n3+1023)/1024;

  char* w = (char*)d_ws;
  size_t off = 0;
  auto alloc = [&](size_t bytes)->char*{ char* p = w + off; off += (bytes + 511) & ~511ull; return p; };
  f16*   xb0    = (f16*)alloc((size_t)N*128*2);       // ping (25.6 MB)
  f16*   xb1    = (f16*)alloc((size_t)N*128*2);       // pong (25.6 MB)
  f16*   s      = (f16*)alloc((size_t)N*384*2);       // gathered sums (76.8 MB)
  int*   deg3   = (int*)alloc((size_t)n3*4);
  int*   part   = (int*)alloc((size_t)n3*4);
  int*   rp3    = (int*)alloc((size_t)(n3+1)*4);
  int*   cursor = (int*)alloc((size_t)n3*4);
  int*   pay    = (int*)alloc((size_t)E*4);
  int*   bsum   = (int*)alloc((size_t)nch*4);
  int*   carry  = (int*)alloc((size_t)nch*4);
  float* Wc     = (float*)alloc((size_t)147456*4);
  f16*   WpF    = (f16*)alloc((size_t)(GI_F+GH_F)*2);
  float* mbp    = (float*)alloc((size_t)1152*4);
  float* pooled = (float*)alloc(64*128*4);
  if(off > ws_size){
    k_diag<<<1,64,0,stream>>>(out, out_size, 1.0e6f + (float)(ws_size>>20));
    return;
  }

  const int tb = 256;
  hipMemsetAsync(deg3, 0, (size_t)n3*4, stream);
  k_wcomb   <<<576, 256, 0, stream>>>(W_ih, msg_W, Wc);
  k_mbp     <<<5, 256, 0, stream>>>(W_ih, msg_b, mbp);
  k_wprep   <<<(GI_F+GH_F+255)/256, 256, 0, stream>>>(Wc, W_hh, WpF);
  k_hist3   <<<(E+tb-1)/tb, tb, 0, stream>>>(dst, edge_type, deg3, E);
  k_scan1   <<<nch, 256, 0, stream>>>(deg3, n3, part, bsum);
  k_scan2   <<<1, 64, 0, stream>>>(bsum, nch, carry);
  k_finalize<<<(n3+tb-1)/tb, tb, 0, stream>>>(part, deg3, carry, n3, rp3, cursor);
  k_fill3   <<<(E+tb-1)/tb, tb, 0, stream>>>(src, dst, edge_type, cursor, pay, E);
  k_embed   <<<N, 128, 0, stream>>>(x_type, x_tok, x_small, type_emb, tok_emb, xb0, N);

  int nblk = (N+31)/32;
  f16* xin = xb0;
  f16* xout = xb1;
  for(int it=0; it<8; it++){
    k_gather3_b<<<(N+3)/4, 256, 0, stream>>>(xin, rp3, pay, s, N);
    k_mega2    <<<nblk, 256, 0, stream>>>(xin, xout, s, WpF, deg3, mbp, b_ih, b_hh, N);
    f16* tmp = xin; xin = xout; xout = tmp;
  }
  // final state is in xin after the swap
  hipMemsetAsync(pooled, 0, 64*128*4, stream);
  k_pool2<<<dim3(64,32), 128, 0, stream>>>(xin, batch, pooled, N);
  k_head <<<64, 128, 0, stream>>>(pooled, batch, N, pW1, pb1, pW2, pb2, out);
}